// Round 9
// baseline (95.648 us; speedup 1.0000x reference)
//
#include <hip/hip_runtime.h>

// N=4096 rows, D=128 in-dim, P=128 pe-dim, H=256 hidden.
// out: (N, 129) fp32, col 0 = ones, col j+1 = x[:,j] * (1 + g_j)
//
//   base[n][h] = sum_i x[n][i]*W1[i][h] + b1[h]          (kernel 1 -> d_ws)
//   g = sum_h relu(base[n][h] + W1[128+j][h] - x[n][j]*W1[j][h]) * W2[h] + b2
//   out[n][1+j] = x[n][j] * (1 + g)

#define NROWS 4096
#define DIN   128
#define HDIM  256
#define JCH   8     // j's per block
#define RPB   256   // rows per block (4 per lane): 4x fewer W1 SMEM re-reads

typedef float sfloat16 __attribute__((ext_vector_type(16)));

// ---------------- Kernel 1: base = x @ W1[:128] + b1 ----------------
// (r5 form, unchanged — ~4 us, not the bottleneck)
__global__ __launch_bounds__(256) void nimo_base(
    const float* __restrict__ x, const float* __restrict__ W1,
    const float* __restrict__ b1, float* __restrict__ baseb)
{
    __shared__ float xs[DIN * 36];
    const int tid  = threadIdx.x;
    const int row0 = blockIdx.x * 32;
    const int h0   = blockIdx.y * 64;

    {
        const int bidx = tid * 16;
        const int r = bidx >> 7;
        const int c = bidx & 127;
        #pragma unroll
        for (int u = 0; u < 4; ++u) {
            const float4 v = *(const float4*)(x + (size_t)(row0 + r) * DIN + c + u * 4);
            xs[(c + u * 4 + 0) * 36 + r] = v.x;
            xs[(c + u * 4 + 1) * 36 + r] = v.y;
            xs[(c + u * 4 + 2) * 36 + r] = v.z;
            xs[(c + u * 4 + 3) * 36 + r] = v.w;
        }
    }
    __syncthreads();

    const int tx = tid & 31;
    const int ty = tid >> 5;
    const float* __restrict__ wcol = W1 + h0 + tx * 2;

    float2 acc[4];
    #pragma unroll
    for (int u = 0; u < 4; ++u) { acc[u].x = 0.f; acc[u].y = 0.f; }

    #pragma unroll 8
    for (int k = 0; k < DIN; ++k) {
        const float2 w  = *(const float2*)(wcol + (size_t)k * HDIM);
        const float4 xv = *(const float4*)(&xs[k * 36 + ty * 4]);
        acc[0].x = fmaf(xv.x, w.x, acc[0].x); acc[0].y = fmaf(xv.x, w.y, acc[0].y);
        acc[1].x = fmaf(xv.y, w.x, acc[1].x); acc[1].y = fmaf(xv.y, w.y, acc[1].y);
        acc[2].x = fmaf(xv.z, w.x, acc[2].x); acc[2].y = fmaf(xv.z, w.y, acc[2].y);
        acc[3].x = fmaf(xv.w, w.x, acc[3].x); acc[3].y = fmaf(xv.w, w.y, acc[3].y);
    }

    const float2 bv = *(const float2*)(b1 + h0 + tx * 2);
    #pragma unroll
    for (int u = 0; u < 4; ++u) {
        float2 o; o.x = acc[u].x + bv.x; o.y = acc[u].y + bv.y;
        *(float2*)(baseb + (size_t)(row0 + ty * 4 + u) * HDIM + h0 + tx * 2) = o;
    }
}

// ---------------- Kernel 2: masked-MLP evaluation (row-fused) ----------------
// grid (16, 16) = 256 blocks (1/CU), block 1024 = 16 waves.
// Wave q owns h-chunk [q*16, q*16+16); lane owns 4 rows {r, r+64, r+128, r+192}.
// bb[64] register-resident (constant-index only); W2 chunk in SGPRs.
// W1 rows via 2x s_load_dwordx16 per (wave, 2j-batch x2): total SMEM requests
// cut 4x vs r5-r8 (65536 vs 262144) — the invariant all neutral rounds shared.
// Partials drained every 2 j through part[16][2][258] (33 KB LDS).
__global__ __launch_bounds__(1024, 4) void nimo_main(
    const float* __restrict__ x, const float* __restrict__ W1,
    const float* __restrict__ W2, const float* __restrict__ b2,
    const float* __restrict__ baseb, float* __restrict__ out)
{
    __shared__ float xs[RPB][JCH + 1];     // x tile, stride 9 (all banks, 2-way max)
    __shared__ float part[16][2][RPB + 2]; // per-wave h-partials, 2-j slots

    const int tid  = threadIdx.x;
    const int lane = tid & 63;
    const int q    = tid >> 6;             // wave id 0..15
    const int row0 = blockIdx.x * RPB;
    const int j0   = blockIdx.y * JCH;
    const int h0   = q * 16;

    // stage x tile: 256 rows x 8 j, 2 floats/thread (coalesced float2)
    {
        const int rr = tid >> 2;           // 0..255
        const int jc = (tid & 3) * 2;      // 0,2,4,6
        const float2 v = *(const float2*)(x + (size_t)(row0 + rr) * DIN + j0 + jc);
        xs[rr][jc] = v.x; xs[rr][jc + 1] = v.y;
    }

    // W2 chunk -> SGPRs (wave-uniform)
    unsigned w2off = __builtin_amdgcn_readfirstlane((unsigned)(h0 * 4));
    sfloat16 w2s;
    asm volatile(
        "s_load_dwordx16 %0, %1, 0x0\n\t"
        "s_waitcnt lgkmcnt(0)"
        : "=s"(w2s) : "s"((unsigned long long)(uintptr_t)W2 + w2off));

    // bb[4 rows][16 h] register-resident (scalar assigns -> no scratch)
    float bb[64];
    #pragma unroll
    for (int g = 0; g < 4; ++g) {
        const float* bp = baseb + (size_t)(row0 + g * 64 + lane) * HDIM + h0;
        #pragma unroll
        for (int u = 0; u < 4; ++u) {
            const float4 v = *(const float4*)(bp + u * 4);
            bb[g * 16 + u * 4 + 0] = v.x; bb[g * 16 + u * 4 + 1] = v.y;
            bb[g * 16 + u * 4 + 2] = v.z; bb[g * 16 + u * 4 + 3] = v.w;
        }
    }

    const float b2s = b2[0];
    if (blockIdx.y == 0 && tid < RPB) out[(size_t)(row0 + tid) * 129] = 1.0f;

    // wave-uniform W1 base (j0 row, this wave's h-chunk)
    unsigned off0 = __builtin_amdgcn_readfirstlane((unsigned)((j0 * HDIM + h0) * 4));
    const unsigned long long wbase = (unsigned long long)(uintptr_t)W1 + off0;
    __syncthreads();

    #pragma unroll
    for (int jb = 0; jb < JCH; jb += 2) {
        sfloat16 wa0, wp0, wa1, wp1;
        asm volatile(
            "s_load_dwordx16 %0, %4, %5\n\t"
            "s_load_dwordx16 %1, %4, %6\n\t"
            "s_load_dwordx16 %2, %4, %7\n\t"
            "s_load_dwordx16 %3, %4, %8\n\t"
            "s_waitcnt lgkmcnt(0)"
            : "=s"(wa0), "=s"(wp0), "=s"(wa1), "=s"(wp1)
            : "s"(wbase),
              "i"(jb * 0x400),           "i"(0x20000 + jb * 0x400),
              "i"((jb + 1) * 0x400),     "i"(0x20000 + (jb + 1) * 0x400));

        #pragma unroll
        for (int s = 0; s < 2; ++s) {
            const int jj = jb + s;
            #pragma unroll
            for (int g = 0; g < 4; ++g) {
                const float xj = xs[g * 64 + lane][jj];
                float acc = 0.f;
                #pragma unroll
                for (int h = 0; h < 16; ++h) {
                    const float wph = s ? wp1[h] : wp0[h];
                    const float wah = s ? wa1[h] : wa0[h];
                    float t = bb[g * 16 + h] + wph;   // v_add (1 sgpr)
                    t = fmaf(-xj, wah, t);            // v_fma (1 sgpr)
                    t = fmaxf(t, 0.f);
                    acc = fmaf(t, w2s[h], acc);       // v_fma (1 sgpr)
                }
                part[q][s][g * 64 + lane] = acc;
            }
        }
        __syncthreads();

        // drain: 512 threads cover 256 rows x 2 j
        if (tid < 512) {
            const int rr = tid & 255;
            const int ss = tid >> 8;
            float gsum = 0.f;
            #pragma unroll
            for (int qq = 0; qq < 16; ++qq) gsum += part[qq][ss][rr];
            const float xvv = xs[rr][jb + ss];
            out[(size_t)(row0 + rr) * 129 + 1 + j0 + jb + ss] =
                xvv * (1.0f + gsum + b2s);
        }
        __syncthreads();
    }
}

extern "C" void kernel_launch(void* const* d_in, const int* in_sizes, int n_in,
                              void* d_out, int out_size, void* d_ws, size_t ws_size,
                              hipStream_t stream) {
    const float* x  = (const float*)d_in[0];   // 4096*128
    const float* W1 = (const float*)d_in[1];   // 256*256
    const float* b1 = (const float*)d_in[2];   // 256
    const float* W2 = (const float*)d_in[3];   // 256
    const float* b2 = (const float*)d_in[4];   // 1
    float* out = (float*)d_out;                // 4096*129
    float* baseb = (float*)d_ws;               // 4 MB scratch

    nimo_base<<<dim3(NROWS / 32, HDIM / 64), 256, 0, stream>>>(x, W1, b1, baseb);
    nimo_main<<<dim3(NROWS / RPB, DIN / JCH), 1024, 0, stream>>>(x, W1, W2, b2, baseb, out);
}